// Round 1
// baseline (1856.476 us; speedup 1.0000x reference)
//
#include <hip/hip_runtime.h>
#include <stdint.h>

#define D 128
#define NACT 16
#define LAYERS 3

typedef __attribute__((ext_vector_type(4))) float f32x4;
typedef __attribute__((ext_vector_type(8))) short short8;

__device__ __forceinline__ unsigned short f2bf(float f) {
  union { float f; unsigned int u; } v; v.f = f;
  return (unsigned short)((v.u + 0x7fffu + ((v.u >> 16) & 1u)) >> 16);
}
__device__ __forceinline__ float bf2f(unsigned short s) {
  union { unsigned int u; float f; } v; v.u = ((unsigned int)s) << 16; return v.f;
}
__device__ __forceinline__ f32x4 mfma16(short8 a, short8 b, f32x4 c) {
  return __builtin_amdgcn_mfma_f32_16x16x32_bf16(a, b, c, 0, 0, 0);
}

// ---------------- mask dtype detection ----------------
// Scans first nWords u32 of the mask buffer. bool-bytes -> some word in (1, 0x01010101];
// float32 0/1.0 -> words 0x3F800000 (> 0x01010101); int32 -> all words <= 1.
__global__ void k_detect(const unsigned int* __restrict__ m, int nWords, int* __restrict__ flag) {
  int f = 0;
  for (int i = blockIdx.x * blockDim.x + threadIdx.x; i < nWords; i += gridDim.x * blockDim.x) {
    unsigned int w = m[i];
    if (w > 1u) f |= 1;
    if (w > 0x01010101u) f |= 2;
  }
  if (f) atomicOr(flag, f);
}

// ---------------- weight pack: dst[l][n][k] = bf16(src[l][k][n]) ----------------
__global__ void k_pack(const float* __restrict__ src, unsigned short* __restrict__ dst,
                       int Lc, int K, int N) {
  int total = Lc * K * N;
  for (int i = blockIdx.x * blockDim.x + threadIdx.x; i < total; i += gridDim.x * blockDim.x) {
    int l = i / (K * N);
    int rem = i - l * (K * N);
    int n = rem / K;
    int k = rem - n * K;
    dst[i] = f2bf(src[(l * K + k) * N + n]);
  }
}

// ---------------- merge edge arrays ----------------
__global__ void k_edges(const int* __restrict__ sb, const int* __restrict__ rb, const int* __restrict__ tb,
                        const int* __restrict__ sn, const int* __restrict__ rn, const int* __restrict__ tn,
                        int EBn, int ENn, int nvb,
                        int* __restrict__ s, int* __restrict__ r, int* __restrict__ t) {
  int E = EBn + ENn;
  for (int e = blockIdx.x * blockDim.x + threadIdx.x; e < E; e += gridDim.x * blockDim.x) {
    if (e < EBn) { s[e] = sb[e]; r[e] = rb[e]; t[e] = tb[e]; }
    else { int j = e - EBn; s[e] = sn[j] + nvb; r[e] = rn[j]; t[e] = tn[j]; }
  }
}

// ---------------- variable embedding ----------------
__global__ void k_embed_vars(const int* __restrict__ vtb, const int* __restrict__ vvb,
                             const int* __restrict__ vtn, const float* __restrict__ vvn,
                             const float* __restrict__ pred, const float* __restrict__ bemb,
                             const float* __restrict__ numw, const float* __restrict__ numb,
                             unsigned short* __restrict__ vars, int nvb, int nv) {
  long total = (long)nv * 64;
  for (long t = (long)blockIdx.x * blockDim.x + threadIdx.x; t < total;
       t += (long)gridDim.x * blockDim.x) {
    int row = (int)(t >> 6);
    int c2 = ((int)t & 63) * 2;
    float x0, x1;
    if (row < nvb) {
      int tp = vtb[row], bv = vvb[row];
      x0 = pred[tp * D + c2] + bemb[bv * D + c2];
      x1 = pred[tp * D + c2 + 1] + bemb[bv * D + c2 + 1];
    } else {
      int j = row - nvb;
      int tp = vtn[j];
      float v = vvn[j];
      float a0 = v * numw[c2] + numb[c2];       a0 = a0 > 0.f ? a0 : 0.f;
      float a1 = v * numw[c2 + 1] + numb[c2 + 1]; a1 = a1 > 0.f ? a1 : 0.f;
      x0 = a0 + pred[tp * D + c2];
      x1 = a1 + pred[tp * D + c2 + 1];
    }
    unsigned int packed = (unsigned int)f2bf(x0) | ((unsigned int)f2bf(x1) << 16);
    *(unsigned int*)(vars + (size_t)row * D + c2) = packed;
  }
}

// ---------------- factor embedding ----------------
__global__ void k_embed_facs(const int* __restrict__ fcls, const float* __restrict__ femb,
                             unsigned short* __restrict__ facs, int nf) {
  long total = (long)nf * 64;
  for (long t = (long)blockIdx.x * blockDim.x + threadIdx.x; t < total;
       t += (long)gridDim.x * blockDim.x) {
    int row = (int)(t >> 6);
    int c2 = ((int)t & 63) * 2;
    int c = fcls[row];
    float x0 = femb[c * D + c2];
    float x1 = femb[c * D + c2 + 1];
    unsigned int packed = (unsigned int)f2bf(x0) | ((unsigned int)f2bf(x1) << 16);
    *(unsigned int*)(facs + (size_t)row * D + c2) = packed;
  }
}

// ---------------- edge message GEMM + atomic scatter ----------------
// m = relu((state[gidx[e]] + edge_emb[etype[e]]) @ W); agg[sidx[e]] += m
// Block = 4 waves; each wave owns 2 column tiles (16 cols each). Chunk = 16 edges.
__global__ void __launch_bounds__(256)
k_msg(const unsigned short* __restrict__ state, const int* __restrict__ gidx,
      const int* __restrict__ sidx, const int* __restrict__ etype,
      const float* __restrict__ eemb, const unsigned short* __restrict__ WT,
      float* __restrict__ agg, int nE) {
  int wid = threadIdx.x >> 6;
  int lane = threadIdx.x & 63;
  int r16 = lane & 15;
  int g = lane >> 4;
  int ct0 = wid * 2;

  short8 b[2][4];
#pragma unroll
  for (int c2 = 0; c2 < 2; ++c2)
#pragma unroll
    for (int ks = 0; ks < 4; ++ks)
      b[c2][ks] = *(const short8*)(WT + ((ct0 + c2) * 16 + r16) * D + ks * 32 + g * 8);

  int nChunks = (nE + 15) >> 4;
  for (int ch = blockIdx.x; ch < nChunks; ch += gridDim.x) {
    int ebase = ch * 16;
    int e = ebase + r16;
    int eg = e < nE ? e : nE - 1;
    int gi = gidx[eg];
    int et = etype[eg];
    f32x4 acc0 = {0.f, 0.f, 0.f, 0.f}, acc1 = {0.f, 0.f, 0.f, 0.f};
#pragma unroll
    for (int ks = 0; ks < 4; ++ks) {
      short8 xb = *(const short8*)(state + (size_t)gi * D + ks * 32 + g * 8);
      const float* ep = eemb + et * D + ks * 32 + g * 8;
      f32x4 e0 = *(const f32x4*)ep;
      f32x4 e1 = *(const f32x4*)(ep + 4);
      short8 a;
#pragma unroll
      for (int j = 0; j < 4; ++j) a[j] = (short)f2bf(bf2f((unsigned short)xb[j]) + e0[j]);
#pragma unroll
      for (int j = 0; j < 4; ++j) a[4 + j] = (short)f2bf(bf2f((unsigned short)xb[4 + j]) + e1[j]);
      acc0 = mfma16(a, b[0][ks], acc0);
      acc1 = mfma16(a, b[1][ks], acc1);
    }
#pragma unroll
    for (int j = 0; j < 4; ++j) {
      int rrow = ebase + g * 4 + j;
      if (rrow < nE) {
        int sr = sidx[rrow];
        float v0 = acc0[j] > 0.f ? acc0[j] : 0.f;
        float v1 = acc1[j] > 0.f ? acc1[j] : 0.f;
        atomicAdd(agg + (size_t)sr * D + ct0 * 16 + r16, v0);
        atomicAdd(agg + (size_t)sr * D + (ct0 + 1) * 16 + r16, v1);
      }
    }
  }
}

// ---------------- state update GEMM (in-place) ----------------
// state[r] = relu(concat(state[r], agg[r]) @ W_upd)   K=256, N=128
__global__ void __launch_bounds__(256)
k_upd(unsigned short* __restrict__ state, const float* __restrict__ agg,
      const unsigned short* __restrict__ WT, int nRows) {
  int wid = threadIdx.x >> 6;
  int lane = threadIdx.x & 63;
  int r16 = lane & 15;
  int g = lane >> 4;
  int ct0 = wid * 2;

  short8 b[2][8];
#pragma unroll
  for (int c2 = 0; c2 < 2; ++c2)
#pragma unroll
    for (int ks = 0; ks < 8; ++ks)
      b[c2][ks] = *(const short8*)(WT + ((ct0 + c2) * 16 + r16) * 256 + ks * 32 + g * 8);

  int nChunks = (nRows + 15) >> 4;
  for (int ch = blockIdx.x; ch < nChunks; ch += gridDim.x) {
    int rbase = ch * 16;
    int rr = rbase + r16;
    int rg = rr < nRows ? rr : nRows - 1;
    short8 a[8];
#pragma unroll
    for (int ks = 0; ks < 4; ++ks)
      a[ks] = *(const short8*)(state + (size_t)rg * D + ks * 32 + g * 8);
#pragma unroll
    for (int ks = 0; ks < 4; ++ks) {
      const float* ap = agg + (size_t)rg * D + ks * 32 + g * 8;
      f32x4 f0 = *(const f32x4*)ap;
      f32x4 f1 = *(const f32x4*)(ap + 4);
      short8 t;
#pragma unroll
      for (int j = 0; j < 4; ++j) { t[j] = (short)f2bf(f0[j]); t[4 + j] = (short)f2bf(f1[j]); }
      a[4 + ks] = t;
    }
    __syncthreads();  // all waves hold A in regs before anyone overwrites state
    f32x4 acc0 = {0.f, 0.f, 0.f, 0.f}, acc1 = {0.f, 0.f, 0.f, 0.f};
#pragma unroll
    for (int ks = 0; ks < 8; ++ks) {
      acc0 = mfma16(a[ks], b[0][ks], acc0);
      acc1 = mfma16(a[ks], b[1][ks], acc1);
    }
#pragma unroll
    for (int j = 0; j < 4; ++j) {
      int row = rbase + g * 4 + j;
      if (row < nRows) {
        float v0 = acc0[j] > 0.f ? acc0[j] : 0.f;
        float v1 = acc1[j] > 0.f ? acc1[j] : 0.f;
        state[(size_t)row * D + ct0 * 16 + r16] = f2bf(v0);
        state[(size_t)row * D + (ct0 + 1) * 16 + r16] = f2bf(v1);
      }
    }
  }
}

// ---------------- policy head ----------------
__global__ void __launch_bounds__(256)
k_policy(const unsigned short* __restrict__ facs, const unsigned short* __restrict__ WpT,
         const float* __restrict__ bpol, const void* __restrict__ maskp,
         const int* __restrict__ flag, float* __restrict__ out, int nF) {
  int wid = threadIdx.x >> 6;
  int lane = threadIdx.x & 63;
  int r16 = lane & 15;
  int g = lane >> 4;

  short8 b[4];
#pragma unroll
  for (int ks = 0; ks < 4; ++ks)
    b[ks] = *(const short8*)(WpT + r16 * D + ks * 32 + g * 8);
  float bias = bpol[r16];
  int fl = *flag;

  int nChunks = (nF + 15) >> 4;
  for (int ch = blockIdx.x * 4 + wid; ch < nChunks; ch += gridDim.x * 4) {
    int fbase = ch * 16;
    int fr = fbase + r16;
    int fg = fr < nF ? fr : nF - 1;
    f32x4 acc = {0.f, 0.f, 0.f, 0.f};
#pragma unroll
    for (int ks = 0; ks < 4; ++ks) {
      short8 a = *(const short8*)(facs + (size_t)fg * D + ks * 32 + g * 8);
      acc = mfma16(a, b[ks], acc);
    }
#pragma unroll
    for (int j = 0; j < 4; ++j) {
      int row = fbase + g * 4 + j;
      if (row < nF) {
        float v = acc[j] + bias;
        int mi = row * NACT + r16;
        bool mv;
        if (fl & 2)      mv = ((const float*)maskp)[mi] != 0.0f;
        else if (fl & 1) mv = ((const unsigned char*)maskp)[mi] != 0;
        else             mv = ((const int*)maskp)[mi] != 0;
        out[mi] = mv ? v : -1e9f;
      }
    }
  }
}

extern "C" void kernel_launch(void* const* d_in, const int* in_sizes, int n_in,
                              void* d_out, int out_size, void* d_ws, size_t ws_size,
                              hipStream_t stream) {
  const int*   vtb  = (const int*)d_in[0];
  const int*   vvb  = (const int*)d_in[1];
  const int*   vtn  = (const int*)d_in[2];
  const float* vvn  = (const float*)d_in[3];
  const int*   fcls = (const int*)d_in[4];
  const int*   sb   = (const int*)d_in[5];
  const int*   rb   = (const int*)d_in[6];
  const int*   tb   = (const int*)d_in[7];
  const int*   sn   = (const int*)d_in[8];
  const int*   rn   = (const int*)d_in[9];
  const int*   tn   = (const int*)d_in[10];
  const void*  mask = d_in[11];
  const float* pred = (const float*)d_in[12];
  const float* bemb = (const float*)d_in[13];
  const float* femb = (const float*)d_in[14];
  const float* eemb = (const float*)d_in[15];
  const float* numw = (const float*)d_in[16];
  const float* numb = (const float*)d_in[17];
  const float* Wvf  = (const float*)d_in[18];
  const float* Wuf  = (const float*)d_in[19];
  const float* Wfv  = (const float*)d_in[20];
  const float* Wuv  = (const float*)d_in[21];
  const float* Wpol = (const float*)d_in[22];
  const float* bpol = (const float*)d_in[23];

  int NVB = in_sizes[0], NVN = in_sizes[2], NF = in_sizes[4];
  int EB = in_sizes[5], EN = in_sizes[8];
  int NV = NVB + NVN, E = EB + EN;

  char* ws = (char*)d_ws;
  size_t off = 0;
  auto alloc = [&](size_t bytes) -> char* {
    char* p = ws + off;
    off = (off + bytes + 255) & ~(size_t)255;
    return p;
  };
  unsigned short* vars = (unsigned short*)alloc((size_t)NV * D * 2);
  unsigned short* facs = (unsigned short*)alloc((size_t)NF * D * 2);
  float*          agg  = (float*)alloc((size_t)NV * D * 4);
  int*            es   = (int*)alloc((size_t)E * 4);
  int*            er   = (int*)alloc((size_t)E * 4);
  int*            et   = (int*)alloc((size_t)E * 4);
  unsigned short* WvfT = (unsigned short*)alloc((size_t)LAYERS * D * D * 2);
  unsigned short* WfvT = (unsigned short*)alloc((size_t)LAYERS * D * D * 2);
  unsigned short* WufT = (unsigned short*)alloc((size_t)LAYERS * D * 2 * D * 2);
  unsigned short* WuvT = (unsigned short*)alloc((size_t)LAYERS * D * 2 * D * 2);
  unsigned short* WpT  = (unsigned short*)alloc((size_t)NACT * D * 2);
  int*            flag = (int*)alloc(256);

  hipMemsetAsync(flag, 0, 4, stream);
  k_detect<<<256, 256, 0, stream>>>((const unsigned int*)mask, NF * NACT / 4, flag);
  k_pack<<<64, 256, 0, stream>>>(Wvf, WvfT, LAYERS, D, D);
  k_pack<<<64, 256, 0, stream>>>(Wfv, WfvT, LAYERS, D, D);
  k_pack<<<96, 256, 0, stream>>>(Wuf, WufT, LAYERS, 2 * D, D);
  k_pack<<<96, 256, 0, stream>>>(Wuv, WuvT, LAYERS, 2 * D, D);
  k_pack<<<8, 256, 0, stream>>>(Wpol, WpT, 1, D, NACT);
  k_edges<<<1024, 256, 0, stream>>>(sb, rb, tb, sn, rn, tn, EB, EN, NVB, es, er, et);
  k_embed_vars<<<4096, 256, 0, stream>>>(vtb, vvb, vtn, vvn, pred, bemb, numw, numb, vars, NVB, NV);
  k_embed_facs<<<2048, 256, 0, stream>>>(fcls, femb, facs, NF);

  for (int l = 0; l < LAYERS; ++l) {
    // variable -> factor
    hipMemsetAsync(agg, 0, (size_t)NF * D * 4, stream);
    k_msg<<<2048, 256, 0, stream>>>(vars, es, er, et, eemb, WvfT + (size_t)l * D * D, agg, E);
    k_upd<<<1024, 256, 0, stream>>>(facs, agg, WufT + (size_t)l * D * 2 * D, NF);
    // factor -> variable (skip on last layer: variables don't feed the output)
    if (l < LAYERS - 1) {
      hipMemsetAsync(agg, 0, (size_t)NV * D * 4, stream);
      k_msg<<<2048, 256, 0, stream>>>(facs, er, es, et, eemb, WfvT + (size_t)l * D * D, agg, E);
      k_upd<<<2048, 256, 0, stream>>>(vars, agg, WuvT + (size_t)l * D * 2 * D, NV);
    }
  }
  k_policy<<<1024, 256, 0, stream>>>(facs, WpT, bpol, mask, flag, (float*)d_out, NF);
}

// Round 2
// 1142.155 us; speedup vs baseline: 1.6254x; 1.6254x over previous
//
#include <hip/hip_runtime.h>
#include <stdint.h>

#define D 128
#define NACT 16
#define LAYERS 3
#define SCH 8192

typedef __attribute__((ext_vector_type(4))) float f32x4;
typedef __attribute__((ext_vector_type(8))) short short8;

__device__ __forceinline__ unsigned short f2bf(float f) {
  union { float f; unsigned int u; } v; v.f = f;
  return (unsigned short)((v.u + 0x7fffu + ((v.u >> 16) & 1u)) >> 16);
}
__device__ __forceinline__ float bf2f(unsigned short s) {
  union { unsigned int u; float f; } v; v.u = ((unsigned int)s) << 16; return v.f;
}
__device__ __forceinline__ f32x4 mfma16(short8 a, short8 b, f32x4 c) {
  return __builtin_amdgcn_mfma_f32_16x16x32_bf16(a, b, c, 0, 0, 0);
}

// ---------------- mask dtype detection ----------------
__global__ void k_detect(const unsigned int* __restrict__ m, int nWords, int* __restrict__ flag) {
  int f = 0;
  for (int i = blockIdx.x * blockDim.x + threadIdx.x; i < nWords; i += gridDim.x * blockDim.x) {
    unsigned int w = m[i];
    if (w > 1u) f |= 1;
    if (w > 0x01010101u) f |= 2;
  }
  if (f) atomicOr(flag, f);
}

// ---------------- weight pack: dst[l][n][k] = bf16(src[l][k][n]) ----------------
__global__ void k_pack(const float* __restrict__ src, unsigned short* __restrict__ dst,
                       int Lc, int K, int N) {
  int total = Lc * K * N;
  for (int i = blockIdx.x * blockDim.x + threadIdx.x; i < total; i += gridDim.x * blockDim.x) {
    int l = i / (K * N);
    int rem = i - l * (K * N);
    int n = rem / K;
    int k = rem - n * K;
    dst[i] = f2bf(src[(l * K + k) * N + n]);
  }
}

// ---------------- eW tables: eW[l][dir][t][c] = sum_k eemb[t][k] * W[l][k][c] ----------------
__global__ void k_ew(const float* __restrict__ eemb, const float* __restrict__ Wvf,
                     const float* __restrict__ Wfv, float* __restrict__ eW) {
  int o = blockIdx.x * blockDim.x + threadIdx.x;
  if (o >= LAYERS * 2 * 3 * D) return;
  int c = o & 127;
  int r = o >> 7;
  int t = r % 3; r /= 3;
  int dir = r & 1;
  int l = r >> 1;
  const float* W = (dir == 0 ? Wvf : Wfv) + (size_t)l * D * D;
  float s = 0.f;
  for (int k = 0; k < D; ++k) s += eemb[t * D + k] * W[k * D + c];
  eW[o] = s;
}

// ---------------- CSR build ----------------
__global__ void k_hist(const int* __restrict__ dst, int n, int dadd, int* __restrict__ off) {
  for (int e = blockIdx.x * blockDim.x + threadIdx.x; e < n; e += gridDim.x * blockDim.x)
    atomicAdd(&off[dst[e] + dadd], 1);
}

__global__ void k_scan_sums(const int* __restrict__ data, int n, int* __restrict__ bsum) {
  __shared__ int ts[256];
  int base = blockIdx.x * SCH;
  int s = 0;
  for (int j = threadIdx.x; j < SCH; j += 256) {
    int i = base + j;
    if (i < n) s += data[i];
  }
  ts[threadIdx.x] = s;
  __syncthreads();
  if (threadIdx.x == 0) {
    int tot = 0;
    for (int i = 0; i < 256; ++i) tot += ts[i];
    bsum[blockIdx.x] = tot;
  }
}

__global__ void k_scan_top(int* __restrict__ bsum, int nb) {
  if (threadIdx.x == 0 && blockIdx.x == 0) {
    int run = 0;
    for (int i = 0; i < nb; ++i) { int t = bsum[i]; bsum[i] = run; run += t; }
  }
}

__global__ void k_scan_apply(int* __restrict__ data, int n, const int* __restrict__ bsum) {
  __shared__ int ts[256];
  int base = blockIdx.x * SCH + threadIdx.x * 32;
  int v[32];
  int s = 0;
#pragma unroll
  for (int j = 0; j < 32; ++j) {
    int i = base + j;
    v[j] = (i < n) ? data[i] : 0;
    s += v[j];
  }
  ts[threadIdx.x] = s;
  __syncthreads();
  if (threadIdx.x == 0) {
    int run = 0;
    for (int i = 0; i < 256; ++i) { int t = ts[i]; ts[i] = run; run += t; }
  }
  __syncthreads();
  int run = bsum[blockIdx.x] + ts[threadIdx.x];
#pragma unroll
  for (int j = 0; j < 32; ++j) {
    run += v[j];
    int i = base + j;
    if (i < n) data[i] = run;  // inclusive scan
  }
}

__global__ void k_set1(int* __restrict__ p, int v) {
  if (threadIdx.x == 0 && blockIdx.x == 0) *p = v;
}

// decrement trick: after all scatters, off[d] = exclusive begin of bin d
__global__ void k_scatter(const int* __restrict__ dst, const int* __restrict__ src,
                          const int* __restrict__ ety, int n, int dadd, int sadd,
                          int* __restrict__ off, unsigned* __restrict__ pk) {
  for (int e = blockIdx.x * blockDim.x + threadIdx.x; e < n; e += gridDim.x * blockDim.x) {
    int d = dst[e] + dadd;
    int pos = atomicAdd(&off[d], -1) - 1;
    pk[pos] = (unsigned)(src[e] + sadd) | ((unsigned)ety[e] << 20);
  }
}

// ---------------- variable embedding ----------------
__global__ void k_embed_vars(const int* __restrict__ vtb, const int* __restrict__ vvb,
                             const int* __restrict__ vtn, const float* __restrict__ vvn,
                             const float* __restrict__ pred, const float* __restrict__ bemb,
                             const float* __restrict__ numw, const float* __restrict__ numb,
                             unsigned short* __restrict__ vars, int nvb, int nv) {
  long total = (long)nv * 64;
  for (long t = (long)blockIdx.x * blockDim.x + threadIdx.x; t < total;
       t += (long)gridDim.x * blockDim.x) {
    int row = (int)(t >> 6);
    int c2 = ((int)t & 63) * 2;
    float x0, x1;
    if (row < nvb) {
      int tp = vtb[row], bv = vvb[row];
      x0 = pred[tp * D + c2] + bemb[bv * D + c2];
      x1 = pred[tp * D + c2 + 1] + bemb[bv * D + c2 + 1];
    } else {
      int j = row - nvb;
      int tp = vtn[j];
      float v = vvn[j];
      float a0 = v * numw[c2] + numb[c2];         a0 = a0 > 0.f ? a0 : 0.f;
      float a1 = v * numw[c2 + 1] + numb[c2 + 1]; a1 = a1 > 0.f ? a1 : 0.f;
      x0 = a0 + pred[tp * D + c2];
      x1 = a1 + pred[tp * D + c2 + 1];
    }
    unsigned int packed = (unsigned int)f2bf(x0) | ((unsigned int)f2bf(x1) << 16);
    *(unsigned int*)(vars + (size_t)row * D + c2) = packed;
  }
}

// ---------------- factor embedding ----------------
__global__ void k_embed_facs(const int* __restrict__ fcls, const float* __restrict__ femb,
                             unsigned short* __restrict__ facs, int nf) {
  long total = (long)nf * 64;
  for (long t = (long)blockIdx.x * blockDim.x + threadIdx.x; t < total;
       t += (long)gridDim.x * blockDim.x) {
    int row = (int)(t >> 6);
    int c2 = ((int)t & 63) * 2;
    int c = fcls[row];
    float x0 = femb[c * D + c2];
    float x1 = femb[c * D + c2 + 1];
    unsigned int packed = (unsigned int)f2bf(x0) | ((unsigned int)f2bf(x1) << 16);
    *(unsigned int*)(facs + (size_t)row * D + c2) = packed;
  }
}

// ---------------- xW = state @ W  (bf16 in/out, no relu) ----------------
__global__ void __launch_bounds__(256)
k_xw(const unsigned short* __restrict__ state, const unsigned short* __restrict__ WT,
     unsigned short* __restrict__ xw, int nRows) {
  int wid = threadIdx.x >> 6;
  int lane = threadIdx.x & 63;
  int r16 = lane & 15;
  int g = lane >> 4;
  int ct0 = wid * 2;

  short8 b[2][4];
#pragma unroll
  for (int c2 = 0; c2 < 2; ++c2)
#pragma unroll
    for (int ks = 0; ks < 4; ++ks)
      b[c2][ks] = *(const short8*)(WT + ((ct0 + c2) * 16 + r16) * D + ks * 32 + g * 8);

  int nChunks = (nRows + 15) >> 4;
  for (int ch = blockIdx.x; ch < nChunks; ch += gridDim.x) {
    int rbase = ch * 16;
    int rr = rbase + r16;
    int rg = rr < nRows ? rr : nRows - 1;
    f32x4 acc0 = {0.f, 0.f, 0.f, 0.f}, acc1 = {0.f, 0.f, 0.f, 0.f};
#pragma unroll
    for (int ks = 0; ks < 4; ++ks) {
      short8 a = *(const short8*)(state + (size_t)rg * D + ks * 32 + g * 8);
      acc0 = mfma16(a, b[0][ks], acc0);
      acc1 = mfma16(a, b[1][ks], acc1);
    }
#pragma unroll
    for (int j = 0; j < 4; ++j) {
      int row = rbase + g * 4 + j;
      if (row < nRows) {
        xw[(size_t)row * D + ct0 * 16 + r16] = f2bf(acc0[j]);
        xw[(size_t)row * D + (ct0 + 1) * 16 + r16] = f2bf(acc1[j]);
      }
    }
  }
}

// ---------------- CSR gather-reduce: agg[d] = sum_e relu(xW[src[e]] + eW[t[e]]) ----------------
__global__ void __launch_bounds__(256)
k_agg(const unsigned short* __restrict__ xW, const unsigned* __restrict__ pk,
      const int* __restrict__ off, const float* __restrict__ eW,
      unsigned short* __restrict__ agg, int nDest) {
  int lane = threadIdx.x & 63;
  int c2 = lane * 2;
  int gw = (blockIdx.x * blockDim.x + threadIdx.x) >> 6;
  int nW = (gridDim.x * blockDim.x) >> 6;
  // eW per-lane constants (named scalars: avoid runtime-indexed array -> scratch)
  float e00 = eW[0 * D + c2], e01 = eW[0 * D + c2 + 1];
  float e10 = eW[1 * D + c2], e11 = eW[1 * D + c2 + 1];
  float e20 = eW[2 * D + c2], e21 = eW[2 * D + c2 + 1];

  for (int d = gw; d < nDest; d += nW) {
    int b = off[d], e = off[d + 1];
    float a0 = 0.f, a1 = 0.f;
    for (int i = b; i < e; ++i) {
      unsigned p = pk[i];
      int s = p & 0xFFFFF;
      int t = (int)(p >> 20);
      unsigned w = *(const unsigned*)(xW + (size_t)s * D + c2);
      float w0 = bf2f((unsigned short)(w & 0xFFFF));
      float w1 = bf2f((unsigned short)(w >> 16));
      float ee0 = (t == 0) ? e00 : ((t == 1) ? e10 : e20);
      float ee1 = (t == 0) ? e01 : ((t == 1) ? e11 : e21);
      float v0 = w0 + ee0; v0 = v0 > 0.f ? v0 : 0.f;
      float v1 = w1 + ee1; v1 = v1 > 0.f ? v1 : 0.f;
      a0 += v0; a1 += v1;
    }
    *(unsigned*)(agg + (size_t)d * D + c2) = (unsigned)f2bf(a0) | ((unsigned)f2bf(a1) << 16);
  }
}

// ---------------- state update GEMM (in-place): state = relu(concat(state, agg) @ W) ----------------
__global__ void __launch_bounds__(256)
k_upd(unsigned short* __restrict__ state, const unsigned short* __restrict__ aggb,
      const unsigned short* __restrict__ WT, int nRows) {
  int wid = threadIdx.x >> 6;
  int lane = threadIdx.x & 63;
  int r16 = lane & 15;
  int g = lane >> 4;
  int ct0 = wid * 2;

  short8 b[2][8];
#pragma unroll
  for (int c2 = 0; c2 < 2; ++c2)
#pragma unroll
    for (int ks = 0; ks < 8; ++ks)
      b[c2][ks] = *(const short8*)(WT + ((ct0 + c2) * 16 + r16) * 256 + ks * 32 + g * 8);

  int nChunks = (nRows + 15) >> 4;
  for (int ch = blockIdx.x; ch < nChunks; ch += gridDim.x) {
    int rbase = ch * 16;
    int rr = rbase + r16;
    int rg = rr < nRows ? rr : nRows - 1;
    short8 a[8];
#pragma unroll
    for (int ks = 0; ks < 4; ++ks)
      a[ks] = *(const short8*)(state + (size_t)rg * D + ks * 32 + g * 8);
#pragma unroll
    for (int ks = 0; ks < 4; ++ks)
      a[4 + ks] = *(const short8*)(aggb + (size_t)rg * D + ks * 32 + g * 8);
    __syncthreads();  // all waves hold A in regs before anyone overwrites state
    f32x4 acc0 = {0.f, 0.f, 0.f, 0.f}, acc1 = {0.f, 0.f, 0.f, 0.f};
#pragma unroll
    for (int ks = 0; ks < 8; ++ks) {
      acc0 = mfma16(a[ks], b[0][ks], acc0);
      acc1 = mfma16(a[ks], b[1][ks], acc1);
    }
#pragma unroll
    for (int j = 0; j < 4; ++j) {
      int row = rbase + g * 4 + j;
      if (row < nRows) {
        float v0 = acc0[j] > 0.f ? acc0[j] : 0.f;
        float v1 = acc1[j] > 0.f ? acc1[j] : 0.f;
        state[(size_t)row * D + ct0 * 16 + r16] = f2bf(v0);
        state[(size_t)row * D + (ct0 + 1) * 16 + r16] = f2bf(v1);
      }
    }
  }
}

// ---------------- policy head ----------------
__global__ void __launch_bounds__(256)
k_policy(const unsigned short* __restrict__ facs, const unsigned short* __restrict__ WpT,
         const float* __restrict__ bpol, const void* __restrict__ maskp,
         const int* __restrict__ flag, float* __restrict__ out, int nF) {
  int wid = threadIdx.x >> 6;
  int lane = threadIdx.x & 63;
  int r16 = lane & 15;
  int g = lane >> 4;

  short8 b[4];
#pragma unroll
  for (int ks = 0; ks < 4; ++ks)
    b[ks] = *(const short8*)(WpT + r16 * D + ks * 32 + g * 8);
  float bias = bpol[r16];
  int fl = *flag;

  int nChunks = (nF + 15) >> 4;
  for (int ch = blockIdx.x * 4 + wid; ch < nChunks; ch += gridDim.x * 4) {
    int fbase = ch * 16;
    int fr = fbase + r16;
    int fg = fr < nF ? fr : nF - 1;
    f32x4 acc = {0.f, 0.f, 0.f, 0.f};
#pragma unroll
    for (int ks = 0; ks < 4; ++ks) {
      short8 a = *(const short8*)(facs + (size_t)fg * D + ks * 32 + g * 8);
      acc = mfma16(a, b[ks], acc);
    }
#pragma unroll
    for (int j = 0; j < 4; ++j) {
      int row = fbase + g * 4 + j;
      if (row < nF) {
        float v = acc[j] + bias;
        int mi = row * NACT + r16;
        bool mv;
        if (fl & 2)      mv = ((const float*)maskp)[mi] != 0.0f;
        else if (fl & 1) mv = ((const unsigned char*)maskp)[mi] != 0;
        else             mv = ((const int*)maskp)[mi] != 0;
        out[mi] = mv ? v : -1e9f;
      }
    }
  }
}

extern "C" void kernel_launch(void* const* d_in, const int* in_sizes, int n_in,
                              void* d_out, int out_size, void* d_ws, size_t ws_size,
                              hipStream_t stream) {
  const int*   vtb  = (const int*)d_in[0];
  const int*   vvb  = (const int*)d_in[1];
  const int*   vtn  = (const int*)d_in[2];
  const float* vvn  = (const float*)d_in[3];
  const int*   fcls = (const int*)d_in[4];
  const int*   sb   = (const int*)d_in[5];
  const int*   rb   = (const int*)d_in[6];
  const int*   tb   = (const int*)d_in[7];
  const int*   sn   = (const int*)d_in[8];
  const int*   rn   = (const int*)d_in[9];
  const int*   tn   = (const int*)d_in[10];
  const void*  mask = d_in[11];
  const float* pred = (const float*)d_in[12];
  const float* bemb = (const float*)d_in[13];
  const float* femb = (const float*)d_in[14];
  const float* eemb = (const float*)d_in[15];
  const float* numw = (const float*)d_in[16];
  const float* numb = (const float*)d_in[17];
  const float* Wvf  = (const float*)d_in[18];
  const float* Wuf  = (const float*)d_in[19];
  const float* Wfv  = (const float*)d_in[20];
  const float* Wuv  = (const float*)d_in[21];
  const float* Wpol = (const float*)d_in[22];
  const float* bpol = (const float*)d_in[23];

  int NVB = in_sizes[0], NVN = in_sizes[2], NF = in_sizes[4];
  int EB = in_sizes[5], EN = in_sizes[8];
  int NV = NVB + NVN, E = EB + EN;

  char* ws = (char*)d_ws;
  size_t off_b = 0;
  auto alloc = [&](size_t bytes) -> char* {
    char* p = ws + off_b;
    off_b = (off_b + bytes + 255) & ~(size_t)255;
    return p;
  };
  unsigned short* vars = (unsigned short*)alloc((size_t)NV * D * 2);
  unsigned short* facs = (unsigned short*)alloc((size_t)NF * D * 2);
  unsigned short* xW   = (unsigned short*)alloc((size_t)NV * D * 2);
  unsigned short* agg  = (unsigned short*)alloc((size_t)NV * D * 2);
  unsigned*       pkR  = (unsigned*)alloc((size_t)E * 4);
  unsigned*       pkS  = (unsigned*)alloc((size_t)E * 4);
  int*            offR = (int*)alloc((size_t)(NF + 1) * 4);
  int*            offS = (int*)alloc((size_t)(NV + 1) * 4);
  int*            bsum = (int*)alloc(256 * 4);
  unsigned short* WvfT = (unsigned short*)alloc((size_t)LAYERS * D * D * 2);
  unsigned short* WfvT = (unsigned short*)alloc((size_t)LAYERS * D * D * 2);
  unsigned short* WufT = (unsigned short*)alloc((size_t)LAYERS * D * 2 * D * 2);
  unsigned short* WuvT = (unsigned short*)alloc((size_t)LAYERS * D * 2 * D * 2);
  unsigned short* WpT  = (unsigned short*)alloc((size_t)NACT * D * 2);
  float*          eWt  = (float*)alloc((size_t)LAYERS * 2 * 3 * D * 4);
  int*            flag = (int*)alloc(256);

  // ---- setup: detection, packing, embeddings ----
  hipMemsetAsync(flag, 0, 4, stream);
  k_detect<<<256, 256, 0, stream>>>((const unsigned int*)mask, NF * NACT / 4, flag);
  k_pack<<<64, 256, 0, stream>>>(Wvf, WvfT, LAYERS, D, D);
  k_pack<<<64, 256, 0, stream>>>(Wfv, WfvT, LAYERS, D, D);
  k_pack<<<96, 256, 0, stream>>>(Wuf, WufT, LAYERS, 2 * D, D);
  k_pack<<<96, 256, 0, stream>>>(Wuv, WuvT, LAYERS, 2 * D, D);
  k_pack<<<8, 256, 0, stream>>>(Wpol, WpT, 1, D, NACT);
  k_ew<<<(LAYERS * 2 * 3 * D + 255) / 256, 256, 0, stream>>>(eemb, Wvf, Wfv, eWt);
  k_embed_vars<<<4096, 256, 0, stream>>>(vtb, vvb, vtn, vvn, pred, bemb, numw, numb, vars, NVB, NV);
  k_embed_facs<<<2048, 256, 0, stream>>>(fcls, femb, facs, NF);

  // ---- CSR by receiver (bins = factors) ----
  int nbR = (NF + SCH - 1) / SCH;
  hipMemsetAsync(offR, 0, (size_t)(NF + 1) * 4, stream);
  k_hist<<<1024, 256, 0, stream>>>(rb, EB, 0, offR);
  k_hist<<<1024, 256, 0, stream>>>(rn, EN, 0, offR);
  k_scan_sums<<<nbR, 256, 0, stream>>>(offR, NF, bsum);
  k_scan_top<<<1, 64, 0, stream>>>(bsum, nbR);
  k_scan_apply<<<nbR, 256, 0, stream>>>(offR, NF, bsum);
  k_set1<<<1, 64, 0, stream>>>(offR + NF, E);
  k_scatter<<<1024, 256, 0, stream>>>(rb, sb, tb, EB, 0, 0, offR, pkR);
  k_scatter<<<1024, 256, 0, stream>>>(rn, sn, tn, EN, 0, NVB, offR, pkR);

  // ---- CSR by sender (bins = variables) ----
  int nbS = (NV + SCH - 1) / SCH;
  hipMemsetAsync(offS, 0, (size_t)(NV + 1) * 4, stream);
  k_hist<<<1024, 256, 0, stream>>>(sb, EB, 0, offS);
  k_hist<<<1024, 256, 0, stream>>>(sn, EN, NVB, offS);
  k_scan_sums<<<nbS, 256, 0, stream>>>(offS, NV, bsum);
  k_scan_top<<<1, 64, 0, stream>>>(bsum, nbS);
  k_scan_apply<<<nbS, 256, 0, stream>>>(offS, NV, bsum);
  k_set1<<<1, 64, 0, stream>>>(offS + NV, E);
  k_scatter<<<1024, 256, 0, stream>>>(sb, rb, tb, EB, 0, 0, offS, pkS);
  k_scatter<<<1024, 256, 0, stream>>>(sn, rn, tn, EN, NVB, 0, offS, pkS);

  // ---- GNN layers ----
  for (int l = 0; l < LAYERS; ++l) {
    // variable -> factor
    k_xw<<<2048, 256, 0, stream>>>(vars, WvfT + (size_t)l * D * D, xW, NV);
    k_agg<<<4096, 256, 0, stream>>>(xW, pkR, offR, eWt + (size_t)(l * 2 + 0) * 3 * D, agg, NF);
    k_upd<<<1024, 256, 0, stream>>>(facs, agg, WufT + (size_t)l * D * 2 * D, NF);
    // factor -> variable (skip on last layer: variables don't feed the output)
    if (l < LAYERS - 1) {
      k_xw<<<2048, 256, 0, stream>>>(facs, WfvT + (size_t)l * D * D, xW, NF);
      k_agg<<<4096, 256, 0, stream>>>(xW, pkS, offS, eWt + (size_t)(l * 2 + 1) * 3 * D, agg, NV);
      k_upd<<<2048, 256, 0, stream>>>(vars, agg, WuvT + (size_t)l * D * 2 * D, NV);
    }
  }
  k_policy<<<1024, 256, 0, stream>>>(facs, WpT, bpol, mask, flag, (float*)d_out, NF);
}